// Round 2
// baseline (4834.012 us; speedup 1.0000x reference)
//
#include <hip/hip_runtime.h>
#include <hip/hip_bf16.h>

// ============================================================
// B=32, S=512, IN=3, H=64, D=128, NH=8, DH=16, L=4, C=5
// NSUB=10, MAX_CONSEC=50 -> SDE splits into 11 independent
// segments (state resets to enc at s % 51 == 0).
// Outputs (fp32): logits (160) then sde_features (32*512*64).
// ============================================================

// ---------------- ws layout (float element offsets) ----------------
static constexpr int OFF_TS      = 0;         // 49152
static constexpr int OFF_TIMES   = 49152;     // 16384
static constexpr int OFF_ENCW    = 65536;     // 192
static constexpr int OFF_ENCB    = 65728;     // 64
static constexpr int OFF_ENCG    = 65792;     // 64
static constexpr int OFF_ENCBETA = 65856;     // 64
static constexpr int OFF_DW1     = 65920;     // 8320 (65x128)
static constexpr int OFF_DB1     = 74240;     // 128
static constexpr int OFF_DW2     = 74368;     // 8192 (128x64)
static constexpr int OFF_DB2     = 82560;     // 64
static constexpr int OFF_DW3     = 82624;     // 4096 (64x64)
static constexpr int OFF_DB3     = 86720;     // 64
static constexpr int OFF_AW1     = 86784;     // 64
static constexpr int OFF_AB1     = 86848;     // 64
static constexpr int OFF_AW2     = 86912;     // 4096
static constexpr int OFF_AB2     = 91008;     // 64
static constexpr int OFF_BW1     = 91072;     // 64
static constexpr int OFF_BB1     = 91136;     // 64
static constexpr int OFF_BW2     = 91200;     // 4096
static constexpr int OFF_BB2     = 95296;     // 64
static constexpr int OFF_MD      = 95360;     // 1
static constexpr int OFF_INW     = 95424;     // 8192 (64x128)
static constexpr int OFF_INB     = 103616;    // 128
static constexpr int OFF_WQ      = 103744;    // 4*128*128
static constexpr int OFF_BQ      = 169280;    // 4*128
static constexpr int OFF_WK      = 169792;
static constexpr int OFF_BK      = 235328;
static constexpr int OFF_WV      = 235840;
static constexpr int OFF_BV      = 301376;
static constexpr int OFF_WO      = 301888;
static constexpr int OFF_BO      = 367424;
static constexpr int OFF_LN1G    = 367936;    // 4*128
static constexpr int OFF_LN1B    = 368448;
static constexpr int OFF_LN2G    = 368960;
static constexpr int OFF_LN2B    = 369472;
static constexpr int OFF_FW1     = 369984;    // 4*128*512
static constexpr int OFF_FB1     = 632128;    // 4*512
static constexpr int OFF_FW2     = 634176;    // 4*512*128
static constexpr int OFF_FB2     = 896320;    // 4*128
static constexpr int OFF_CW1     = 896832;    // 128*64
static constexpr int OFF_CB1     = 905024;    // 64
static constexpr int OFF_CW2     = 905088;    // 64*5 (pad)
static constexpr int OFF_CB2     = 905472;    // 5 (pad)
static constexpr int OFF_FLAG    = 905536;    // int flag: 1 = noise is bf16
// compute buffers
static constexpr int OFF_ENC     = 905600;    // 32*512*64
static constexpr int OFF_SDE     = 1954176;   // 32*512*64
static constexpr int OFF_COEFA   = 3002752;   // 5110*64
static constexpr int OFF_COEFB   = 3329792;   // 5110*64
static constexpr int OFF_B1C     = 3656832;   // 5110*128
static constexpr int OFF_X       = 4310912;   // 16384*128
static constexpr int OFF_QB      = 6408064;
static constexpr int OFF_KB      = 8505216;
static constexpr int OFF_VB      = 10602368;
static constexpr int OFF_OB      = 12699520;
static constexpr int OFF_HB      = 14796672;  // 16384*512
static constexpr int OFF_TMP     = 23185280;  // 16384*128
// total = 25282432 floats ~= 96.5 MiB

struct PtrPack { const void* p[45]; };

// ---------------- helpers ----------------
__device__ inline float wsum64(float v) {
#pragma unroll
  for (int off = 32; off > 0; off >>= 1) v += __shfl_xor(v, off, 64);
  return v;
}

__device__ inline float fast_tanh(float x) {
  x = fminf(fmaxf(x, -15.f), 15.f);
  float e = __expf(2.f * x);
  return (e - 1.f) / (e + 1.f);
}

__device__ inline float bfdec(unsigned short h) {
  return __uint_as_float(((unsigned)h) << 16);
}

// ---------------- ingest: convert all float inputs to f32 mirrors ----------------
// Per-array dtype detection: global mode from enc_g (all-ones pattern); in bf16
// mode, each array's leading ushorts are sanity-probed. A genuine-fp32 array
// misread as bf16 yields wild-exponent halves (fp32 0.1 -> 0xCCCD -> -1.07e8),
// flipping that array (e.g. a mixed fp32 scalar) back to fp32 reads. All-zero
// arrays are value-identical under either interpretation.
__global__ __launch_bounds__(256) void ingest_kernel(PtrPack pk, float* __restrict__ W) {
  const int NE = 43;
  const int cnt[NE] = {49152,16384,192,64,64,64,8320,128,8192,64,4096,64,64,64,4096,64,
                       64,64,4096,64,1,8192,128,65536,512,65536,512,65536,512,65536,512,
                       512,512,512,512,262144,2048,262144,512,8192,64,320,5};
  const int src[NE] = {0,1,4,5,6,7,8,9,10,11,12,13,14,15,16,17,18,19,20,21,22,23,24,
                       25,26,27,28,29,30,31,32,33,34,35,36,37,38,39,40,41,42,43,44};
  const int dst[NE] = {OFF_TS,OFF_TIMES,OFF_ENCW,OFF_ENCB,OFF_ENCG,OFF_ENCBETA,OFF_DW1,
                       OFF_DB1,OFF_DW2,OFF_DB2,OFF_DW3,OFF_DB3,OFF_AW1,OFF_AB1,OFF_AW2,
                       OFF_AB2,OFF_BW1,OFF_BB1,OFF_BW2,OFF_BB2,OFF_MD,OFF_INW,OFF_INB,
                       OFF_WQ,OFF_BQ,OFF_WK,OFF_BK,OFF_WV,OFF_BV,OFF_WO,OFF_BO,
                       OFF_LN1G,OFF_LN1B,OFF_LN2G,OFF_LN2B,OFF_FW1,OFF_FB1,OFF_FW2,
                       OFF_FB2,OFF_CW1,OFF_CB1,OFF_CW2,OFF_CB2};
  const unsigned* eg = (const unsigned*)pk.p[6];     // enc_g (all ones)
  int gmode = (eg[0] == 0x3F803F80u) ? 1 : 0;

  __shared__ int isbf[NE];
  if (threadIdx.x < NE) {
    int k = threadIdx.x;
    int f = gmode;
    if (gmode) {
      const unsigned short* us = (const unsigned short*)pk.p[src[k]];
      int n = cnt[k] < 32 ? cnt[k] : 32;   // safe: buffer has >= 2*cnt bytes
      for (int i = 0; i < n; ++i) {
        unsigned short h = us[i];
        if (h & 0x7FFF) {
          float a = fabsf(bfdec(h));
          if (!(a > 1e-20f && a < 1e4f)) { f = 0; break; }
        }
      }
    }
    isbf[k] = f;
  }
  __syncthreads();

  int gid = blockIdx.x * 256 + threadIdx.x;
  if (gid == 0) {
    // noise (input 2) dtype flag for sde_kernel
    int nf = gmode;
    if (gmode) {
      const unsigned short* us = (const unsigned short*)pk.p[2];
      for (int i = 0; i < 32; ++i) {
        unsigned short h = us[i];
        if (h & 0x7FFF) {
          float a = fabsf(bfdec(h));
          if (!(a > 1e-20f && a < 1e4f)) { nf = 0; break; }
        }
      }
    }
    ((int*)W)[OFF_FLAG] = nf;
  }

  const int TOT = 905350;
  int stride = gridDim.x * 256;
  for (int e = gid; e < TOT; e += stride) {
    int rem = e, k = 0;
    while (rem >= cnt[k]) { rem -= cnt[k]; ++k; }
    float v;
    if (isbf[k]) v = bfdec(((const unsigned short*)pk.p[src[k]])[rem]);
    else         v = ((const float*)pk.p[src[k]])[rem];
    W[dst[k] + rem] = v;
  }
}

// ---------------- encoder: enc = relu(LN(ts @ enc_w + enc_b)) ----------------
__global__ __launch_bounds__(64) void encoder_kernel(float* __restrict__ W,
                                                     float* __restrict__ outf) {
  int row = blockIdx.x;        // b*512 + s
  int j = threadIdx.x;
  float t0 = W[OFF_TS + row*3 + 0];
  float t1 = W[OFF_TS + row*3 + 1];
  float t2 = W[OFF_TS + row*3 + 2];
  float v = W[OFF_ENCB + j] + t0 * W[OFF_ENCW + j] + t1 * W[OFF_ENCW + 64 + j]
          + t2 * W[OFF_ENCW + 128 + j];
  float mean = wsum64(v) * (1.f / 64.f);
  float d = v - mean;
  float var = wsum64(d * d) * (1.f / 64.f);
  float o = d * rsqrtf(var + 1e-5f) * W[OFF_ENCG + j] + W[OFF_ENCBETA + j];
  o = fmaxf(o, 0.f);
  W[OFF_ENC + row*64 + j] = o;
  int s = row & 511;
  if (s % 51 == 0) {   // skip/reset positions: sde_features[:,s] = enc[:,s]
    W[OFF_SDE + row*64 + j] = o;
    outf[160 + row*64 + j] = o;
  }
}

// ---------------- precompute A(t), Bt(t), bias1(t) for all 5110 (step,sub) ----------------
__global__ __launch_bounds__(128) void precompute_kernel(float* __restrict__ W) {
  int bi = blockIdx.x;             // 0..5109
  int step = bi / 10, k = bi - step * 10;
  float t_prev = W[OFF_TIMES + step];
  float t_cur  = W[OFF_TIMES + step + 1];
  float h = (t_cur - t_prev) * 0.1f;
  float t = t_prev + (float)k * h;
  __shared__ float av[64], bv[64];
  int tid = threadIdx.x;
  if (tid < 64) av[tid] = fast_tanh(t * W[OFF_AW1 + tid] + W[OFF_AB1 + tid]);
  else { int j = tid - 64; bv[j] = fast_tanh(t * W[OFF_BW1 + j] + W[OFF_BB1 + j]); }
  __syncthreads();
  if (tid < 64) {
    float a = W[OFF_AB2 + tid];
    for (int i = 0; i < 64; ++i) a += av[i] * W[OFF_AW2 + i*64 + tid];
    W[OFF_COEFA + bi*64 + tid] = fmaxf(a, 0.f) + log1pf(__expf(-fabsf(a)));
  } else {
    int j = tid - 64;
    float a = W[OFF_BB2 + j];
    for (int i = 0; i < 64; ++i) a += bv[i] * W[OFF_BW2 + i*64 + j];
    W[OFF_COEFB + bi*64 + j] = fast_tanh(a);
  }
  W[OFF_B1C + bi*128 + tid] = t * W[OFF_DW1 + 64*128 + tid] + W[OFF_DB1 + tid];
}

// ---------------- SDE integrator: 22 blocks = 11 segments x 2 batch halves ----------------
__global__ __launch_bounds__(256) void sde_kernel(float* __restrict__ W,
                                                  const void* __restrict__ noise,
                                                  float* __restrict__ outf) {
  __shared__ float w1s[8192];      // 64x128 fp32
  __shared__ float w2s[8192];      // 128x64
  __shared__ float w3s[4096];      // 64x64
  __shared__ float ybuf[1024];     // 16x64
  __shared__ float h1buf[2048];    // 16x128
  __shared__ float h2buf[1024];    // 16x64
  __shared__ float cAs[64], cBs[64], b1s[128], db2s[64], db3s[64];

  int tid = threadIdx.x;
  int g = blockIdx.x >> 1;         // segment 0..10
  int r0 = (blockIdx.x & 1) * 16;  // batch rows r0..r0+15

  int nmode = ((const int*)W)[OFF_FLAG];
  float md = fabsf(W[OFF_MD]);
  const unsigned short* nb16 = (const unsigned short*)noise;
  const float* nf32 = (const float*)noise;

  for (int u = tid; u < 8192; u += 256) w1s[u] = W[OFF_DW1 + u];  // first 64 rows
  for (int u = tid; u < 8192; u += 256) w2s[u] = W[OFF_DW2 + u];
  for (int u = tid; u < 4096; u += 256) w3s[u] = W[OFF_DW3 + u];
  if (tid < 64) { db2s[tid] = W[OFF_DB2 + tid]; db3s[tid] = W[OFF_DB3 + tid]; }
  for (int q = tid; q < 1024; q += 256) {
    int r = q >> 6, j = q & 63;
    ybuf[q] = W[OFF_ENC + ((r0 + r)*512 + 51*g)*64 + j];
  }

  int nsteps = (g == 10) ? 1 : 50;
  for (int m = 0; m < nsteps; ++m) {
    int istep = 51*g + m;
    float t_prev = W[OFF_TIMES + istep];
    float t_cur  = W[OFF_TIMES + istep + 1];
    float hstep = (t_cur - t_prev) * 0.1f;
    float sqh = sqrtf(hstep);
    for (int k = 0; k < 10; ++k) {
      __syncthreads();
      int ci = istep*10 + k;
      if (tid < 64)       cAs[tid]       = W[OFF_COEFA + ci*64 + tid];
      else if (tid < 128) cBs[tid - 64]  = W[OFF_COEFB + ci*64 + (tid - 64)];
      else                b1s[tid - 128] = W[OFF_B1C + ci*128 + (tid - 128)];
      __syncthreads();
      // ---- stage 1: h1 = tanh(y @ w1 + bias1) ----
      {
        int r = tid >> 4, jg = tid & 15, j0 = jg * 8;
        float yr[64];
#pragma unroll
        for (int ii = 0; ii < 16; ++ii)
          *(float4*)&yr[ii*4] = *(const float4*)&ybuf[r*64 + ii*4];
        float acc[8];
#pragma unroll
        for (int c = 0; c < 8; ++c) acc[c] = b1s[j0 + c];
#pragma unroll
        for (int i = 0; i < 64; ++i) {
          float yv = yr[i];
          float4 wa = *(const float4*)&w1s[i*128 + j0];
          float4 wb = *(const float4*)&w1s[i*128 + j0 + 4];
          acc[0] += yv * wa.x; acc[1] += yv * wa.y;
          acc[2] += yv * wa.z; acc[3] += yv * wa.w;
          acc[4] += yv * wb.x; acc[5] += yv * wb.y;
          acc[6] += yv * wb.z; acc[7] += yv * wb.w;
        }
#pragma unroll
        for (int c = 0; c < 8; ++c) h1buf[r*128 + j0 + c] = fast_tanh(acc[c]);
      }
      __syncthreads();
      // ---- stage 2: h2 = tanh(h1 @ w2 + db2) ----
      {
        int r = tid >> 4, jg = tid & 15, j0 = jg * 4;
        float acc[4];
#pragma unroll
        for (int c = 0; c < 4; ++c) acc[c] = db2s[j0 + c];
#pragma unroll 16
        for (int kk = 0; kk < 128; ++kk) {
          float hv = h1buf[r*128 + kk];
          float4 w = *(const float4*)&w2s[kk*64 + j0];
          acc[0] += hv * w.x; acc[1] += hv * w.y;
          acc[2] += hv * w.z; acc[3] += hv * w.w;
        }
#pragma unroll
        for (int c = 0; c < 4; ++c) h2buf[r*64 + j0 + c] = fast_tanh(acc[c]);
      }
      __syncthreads();
      // ---- stage 3: drift = h2 @ w3 + db3; Euler-Maruyama update ----
      {
        int r = tid >> 4, jg = tid & 15, j0 = jg * 4;
        float acc[4];
#pragma unroll
        for (int c = 0; c < 4; ++c) acc[c] = db3s[j0 + c];
#pragma unroll 16
        for (int i = 0; i < 64; ++i) {
          float hv = h2buf[r*64 + i];
          float4 w = *(const float4*)&w3s[i*64 + j0];
          acc[0] += hv * w.x; acc[1] += hv * w.y;
          acc[2] += hv * w.z; acc[3] += hv * w.w;
        }
        int bb = r0 + r;
        int nbase = (((istep + 1)*10 + k)*32 + bb)*64 + j0;
#pragma unroll
        for (int c = 0; c < 4; ++c) {
          int j = j0 + c;
          float yv = ybuf[r*64 + j];
          float dwv = nmode ? bfdec(nb16[nbase + c]) : nf32[nbase + c];
          ybuf[r*64 + j] = yv + acc[c]*hstep + (cAs[j] + cBs[j]*yv + md)*sqh*dwv;
        }
      }
    }
    // write sde_features[:, istep+1]
    {
      int r = tid >> 4, jg = tid & 15, j0 = jg * 4;
#pragma unroll
      for (int c = 0; c < 4; ++c) {
        int j = j0 + c;
        float v = ybuf[r*64 + j];
        int gi = ((r0 + r)*512 + (istep + 1))*64 + j;
        W[OFF_SDE + gi] = v;
        outf[160 + gi] = v;
      }
    }
  }
}

// ---------------- generic fp32 GEMM: C = act(A[MxK] @ B[KxN] + bias) ----------------
__global__ __launch_bounds__(256) void gemm_kernel(const float* __restrict__ A,
    const float* __restrict__ Bm, const float* __restrict__ bias,
    float* __restrict__ C, int M, int N, int K, int act) {
  __shared__ float As[16][68];   // [kk][m], padded
  __shared__ float Bs[16][64];
  int bm = blockIdx.x * 64, bn = blockIdx.y * 64;
  int tid = threadIdx.x;
  int tm = tid >> 4, tn = tid & 15;
  int aRow = tid >> 2, aK = (tid & 3) * 4;
  int bK = tid >> 4, bN = (tid & 15) * 4;
  float acc[4][4];
#pragma unroll
  for (int i = 0; i < 4; ++i)
#pragma unroll
    for (int j = 0; j < 4; ++j) acc[i][j] = 0.f;
  for (int k0 = 0; k0 < K; k0 += 16) {
    __syncthreads();
    float4 av = *(const float4*)&A[(bm + aRow)*K + k0 + aK];
    As[aK + 0][aRow] = av.x; As[aK + 1][aRow] = av.y;
    As[aK + 2][aRow] = av.z; As[aK + 3][aRow] = av.w;
    *(float4*)&Bs[bK][bN] = *(const float4*)&Bm[(k0 + bK)*N + bn + bN];
    __syncthreads();
#pragma unroll
    for (int kk = 0; kk < 16; ++kk) {
      float4 a  = *(const float4*)&As[kk][tm*4];
      float4 bv = *(const float4*)&Bs[kk][tn*4];
      acc[0][0] += a.x*bv.x; acc[0][1] += a.x*bv.y; acc[0][2] += a.x*bv.z; acc[0][3] += a.x*bv.w;
      acc[1][0] += a.y*bv.x; acc[1][1] += a.y*bv.y; acc[1][2] += a.y*bv.z; acc[1][3] += a.y*bv.w;
      acc[2][0] += a.z*bv.x; acc[2][1] += a.z*bv.y; acc[2][2] += a.z*bv.z; acc[2][3] += a.z*bv.w;
      acc[3][0] += a.w*bv.x; acc[3][1] += a.w*bv.y; acc[3][2] += a.w*bv.z; acc[3][3] += a.w*bv.w;
    }
  }
  float4 bb = *(const float4*)&bias[bn + tn*4];
#pragma unroll
  for (int i = 0; i < 4; ++i) {
    int row = bm + tm*4 + i;
    float4 v;
    v.x = acc[i][0] + bb.x; v.y = acc[i][1] + bb.y;
    v.z = acc[i][2] + bb.z; v.w = acc[i][3] + bb.w;
    if (act) { v.x = fmaxf(v.x, 0.f); v.y = fmaxf(v.y, 0.f);
               v.z = fmaxf(v.z, 0.f); v.w = fmaxf(v.w, 0.f); }
    *(float4*)&C[row*N + bn + tn*4] = v;
  }
}

// ---------------- flash-style attention, DH=16, one wave per 64 q-rows ----------------
__global__ __launch_bounds__(64) void attn_kernel(const float* __restrict__ Q,
    const float* __restrict__ K, const float* __restrict__ V, float* __restrict__ O) {
  int blk = blockIdx.x;
  int qt = blk & 7;
  int h  = (blk >> 3) & 7;
  int b  = blk >> 6;
  int tid = threadIdx.x;
  int qrow = b*512 + qt*64 + tid;
  int col0 = h*16;
  float q[16], o[16];
#pragma unroll
  for (int d = 0; d < 16; ++d) { q[d] = Q[qrow*128 + col0 + d]; o[d] = 0.f; }
  float mM = -1e30f, lsum = 0.f;
  __shared__ float kv[64][16];
  __shared__ float vv[64][16];
  for (int kt = 0; kt < 8; ++kt) {
    __syncthreads();
    int krow = b*512 + kt*64 + tid;
#pragma unroll
    for (int d4 = 0; d4 < 4; ++d4) {
      *(float4*)&kv[tid][d4*4] = *(const float4*)&K[krow*128 + col0 + d4*4];
      *(float4*)&vv[tid][d4*4] = *(const float4*)&V[krow*128 + col0 + d4*4];
    }
    __syncthreads();
    float s[64];
    float tmax = -1e30f;
#pragma unroll
    for (int c = 0; c < 64; ++c) {
      float a = 0.f;
#pragma unroll
      for (int d = 0; d < 16; ++d) a += q[d]*kv[c][d];
      a *= 0.25f;       // 1/sqrt(DH)
      s[c] = a;
      tmax = fmaxf(tmax, a);
    }
    float mNew = fmaxf(mM, tmax);
    float alpha = __expf(mM - mNew);
    lsum *= alpha;
#pragma unroll
    for (int d = 0; d < 16; ++d) o[d] *= alpha;
#pragma unroll
    for (int c = 0; c < 64; ++c) {
      float p = __expf(s[c] - mNew);
      lsum += p;
#pragma unroll
      for (int d = 0; d < 16; ++d) o[d] += p*vv[c][d];
    }
    mM = mNew;
  }
  float inv = 1.f / lsum;
#pragma unroll
  for (int d = 0; d < 16; ++d) O[qrow*128 + col0 + d] = o[d]*inv;
}

// ---------------- residual + LayerNorm (D=128) ----------------
__global__ __launch_bounds__(128) void resln_kernel(float* __restrict__ x,
    const float* __restrict__ r, const float* __restrict__ g, const float* __restrict__ bta) {
  int row = blockIdx.x, j = threadIdx.x;
  int idx = row*128 + j;
  float v = x[idx] + r[idx];
  __shared__ float sm[2], sv[2];
  float s = wsum64(v);
  if ((j & 63) == 0) sm[j >> 6] = s;
  __syncthreads();
  float mean = (sm[0] + sm[1]) * (1.f / 128.f);
  float d = v - mean;
  float qq = wsum64(d * d);
  if ((j & 63) == 0) sv[j >> 6] = qq;
  __syncthreads();
  float var = (sv[0] + sv[1]) * (1.f / 128.f);
  x[idx] = d * rsqrtf(var + 1e-5f) * g[j] + bta[j];
}

// ---------------- mean-pool + 2-layer classifier ----------------
__global__ __launch_bounds__(128) void pool_cls_kernel(const float* __restrict__ W,
                                                       float* __restrict__ outf) {
  int b = blockIdx.x, j = threadIdx.x;
  float s = 0.f;
  for (int ss = 0; ss < 512; ++ss) s += W[OFF_X + ((b*512 + ss)*128) + j];
  __shared__ float pooled[128];
  __shared__ float hid[64];
  pooled[j] = s * (1.f / 512.f);
  __syncthreads();
  if (j < 64) {
    float a = W[OFF_CB1 + j];
    for (int i = 0; i < 128; ++i) a += pooled[i] * W[OFF_CW1 + i*64 + j];
    hid[j] = fmaxf(a, 0.f);
  }
  __syncthreads();
  if (j < 5) {
    float a = W[OFF_CB2 + j];
    for (int i = 0; i < 64; ++i) a += hid[i] * W[OFF_CW2 + i*5 + j];
    outf[b*5 + j] = a;
  }
}

// ---------------- launch ----------------
extern "C" void kernel_launch(void* const* d_in, const int* in_sizes, int n_in,
                              void* d_out, int out_size, void* d_ws, size_t ws_size,
                              hipStream_t stream) {
  (void)in_sizes; (void)out_size; (void)ws_size;
  float* W = reinterpret_cast<float*>(d_ws);
  float* outf = reinterpret_cast<float*>(d_out);
  PtrPack pk;
  for (int i = 0; i < 45 && i < n_in; ++i) pk.p[i] = d_in[i];

  ingest_kernel<<<512, 256, 0, stream>>>(pk, W);
  encoder_kernel<<<16384, 64, 0, stream>>>(W, outf);
  precompute_kernel<<<5110, 128, 0, stream>>>(W);
  sde_kernel<<<22, 256, 0, stream>>>(W, d_in[2], outf);

  // x = sde_features @ in_w + in_b
  gemm_kernel<<<dim3(256, 2), 256, 0, stream>>>(W + OFF_SDE, W + OFF_INW, W + OFF_INB,
                                                W + OFF_X, 16384, 128, 64, 0);
  for (int l = 0; l < 4; ++l) {
    gemm_kernel<<<dim3(256, 2), 256, 0, stream>>>(W + OFF_X, W + OFF_WQ + l*16384,
        W + OFF_BQ + l*128, W + OFF_QB, 16384, 128, 128, 0);
    gemm_kernel<<<dim3(256, 2), 256, 0, stream>>>(W + OFF_X, W + OFF_WK + l*16384,
        W + OFF_BK + l*128, W + OFF_KB, 16384, 128, 128, 0);
    gemm_kernel<<<dim3(256, 2), 256, 0, stream>>>(W + OFF_X, W + OFF_WV + l*16384,
        W + OFF_BV + l*128, W + OFF_VB, 16384, 128, 128, 0);
    attn_kernel<<<2048, 64, 0, stream>>>(W + OFF_QB, W + OFF_KB, W + OFF_VB, W + OFF_OB);
    gemm_kernel<<<dim3(256, 2), 256, 0, stream>>>(W + OFF_OB, W + OFF_WO + l*16384,
        W + OFF_BO + l*128, W + OFF_TMP, 16384, 128, 128, 0);
    resln_kernel<<<16384, 128, 0, stream>>>(W + OFF_X, W + OFF_TMP,
        W + OFF_LN1G + l*128, W + OFF_LN1B + l*128);
    gemm_kernel<<<dim3(256, 8), 256, 0, stream>>>(W + OFF_X, W + OFF_FW1 + l*65536,
        W + OFF_FB1 + l*512, W + OFF_HB, 16384, 512, 128, 1);
    gemm_kernel<<<dim3(256, 2), 256, 0, stream>>>(W + OFF_HB, W + OFF_FW2 + l*65536,
        W + OFF_FB2 + l*128, W + OFF_TMP, 16384, 128, 512, 0);
    resln_kernel<<<16384, 128, 0, stream>>>(W + OFF_X, W + OFF_TMP,
        W + OFF_LN2G + l*128, W + OFF_LN2B + l*128);
  }
  pool_cls_kernel<<<32, 128, 0, stream>>>(W, outf);
}

// Round 3
// 2126.516 us; speedup vs baseline: 2.2732x; 2.2732x over previous
//
#include <hip/hip_runtime.h>
#include <hip/hip_bf16.h>

// ============================================================
// B=32, S=512, IN=3, H=64, D=128, NH=8, DH=16, L=4, C=5
// NSUB=10, MAX_CONSEC=50 -> SDE splits into 11 independent
// segments (state resets to enc at s % 51 == 0).
// Outputs (fp32): logits (160) then sde_features (32*512*64).
// R3: sde_kernel rewritten with MFMA 16x16x32 bf16; weights in
// registers as B-frags; activations via padded bf16 LDS.
// ============================================================

typedef __attribute__((ext_vector_type(8))) short short8;
typedef __attribute__((ext_vector_type(4))) float f32x4;

// ---------------- ws layout (float element offsets) ----------------
static constexpr int OFF_TS      = 0;         // 49152
static constexpr int OFF_TIMES   = 49152;     // 16384
static constexpr int OFF_ENCW    = 65536;     // 192
static constexpr int OFF_ENCB    = 65728;     // 64
static constexpr int OFF_ENCG    = 65792;     // 64
static constexpr int OFF_ENCBETA = 65856;     // 64
static constexpr int OFF_DW1     = 65920;     // 8320 (65x128)
static constexpr int OFF_DB1     = 74240;     // 128
static constexpr int OFF_DW2     = 74368;     // 8192 (128x64)
static constexpr int OFF_DB2     = 82560;     // 64
static constexpr int OFF_DW3     = 82624;     // 4096 (64x64)
static constexpr int OFF_DB3     = 86720;     // 64
static constexpr int OFF_AW1     = 86784;     // 64
static constexpr int OFF_AB1     = 86848;     // 64
static constexpr int OFF_AW2     = 86912;     // 4096
static constexpr int OFF_AB2     = 91008;     // 64
static constexpr int OFF_BW1     = 91072;     // 64
static constexpr int OFF_BB1     = 91136;     // 64
static constexpr int OFF_BW2     = 91200;     // 4096
static constexpr int OFF_BB2     = 95296;     // 64
static constexpr int OFF_MD      = 95360;     // 1
static constexpr int OFF_INW     = 95424;     // 8192 (64x128)
static constexpr int OFF_INB     = 103616;    // 128
static constexpr int OFF_WQ      = 103744;    // 4*128*128
static constexpr int OFF_BQ      = 169280;    // 4*128
static constexpr int OFF_WK      = 169792;
static constexpr int OFF_BK      = 235328;
static constexpr int OFF_WV      = 235840;
static constexpr int OFF_BV      = 301376;
static constexpr int OFF_WO      = 301888;
static constexpr int OFF_BO      = 367424;
static constexpr int OFF_LN1G    = 367936;    // 4*128
static constexpr int OFF_LN1B    = 368448;
static constexpr int OFF_LN2G    = 368960;
static constexpr int OFF_LN2B    = 369472;
static constexpr int OFF_FW1     = 369984;    // 4*128*512
static constexpr int OFF_FB1     = 632128;    // 4*512
static constexpr int OFF_FW2     = 634176;    // 4*512*128
static constexpr int OFF_FB2     = 896320;    // 4*128
static constexpr int OFF_CW1     = 896832;    // 128*64
static constexpr int OFF_CB1     = 905024;    // 64
static constexpr int OFF_CW2     = 905088;    // 64*5 (pad)
static constexpr int OFF_CB2     = 905472;    // 5 (pad)
static constexpr int OFF_FLAG    = 905536;    // int flag: 1 = noise is bf16
// compute buffers
static constexpr int OFF_ENC     = 905600;    // 32*512*64
static constexpr int OFF_SDE     = 1954176;   // 32*512*64
static constexpr int OFF_COEFA   = 3002752;   // 5110*64
static constexpr int OFF_COEFB   = 3329792;   // 5110*64
static constexpr int OFF_B1C     = 3656832;   // 5110*128
static constexpr int OFF_X       = 4310912;   // 16384*128
static constexpr int OFF_QB      = 6408064;
static constexpr int OFF_KB      = 8505216;
static constexpr int OFF_VB      = 10602368;
static constexpr int OFF_OB      = 12699520;
static constexpr int OFF_HB      = 14796672;  // 16384*512
static constexpr int OFF_TMP     = 23185280;  // 16384*128
// total = 25282432 floats ~= 96.5 MiB

struct PtrPack { const void* p[45]; };

// ---------------- helpers ----------------
__device__ inline float wsum64(float v) {
#pragma unroll
  for (int off = 32; off > 0; off >>= 1) v += __shfl_xor(v, off, 64);
  return v;
}

__device__ inline float fast_tanh(float x) {
  x = fminf(fmaxf(x, -15.f), 15.f);
  float e = __expf(2.f * x);
  return (e - 1.f) / (e + 1.f);
}

__device__ inline float bfdec(unsigned short h) {
  return __uint_as_float(((unsigned)h) << 16);
}

// round-to-nearest-even f32 -> bf16 bits
__device__ inline short f2bf(float f) {
  unsigned u = __float_as_uint(f);
  return (short)((u + 0x7FFFu + ((u >> 16) & 1u)) >> 16);
}

// ---------------- ingest: convert all float inputs to f32 mirrors ----------------
__global__ __launch_bounds__(256) void ingest_kernel(PtrPack pk, float* __restrict__ W) {
  const int NE = 43;
  const int cnt[NE] = {49152,16384,192,64,64,64,8320,128,8192,64,4096,64,64,64,4096,64,
                       64,64,4096,64,1,8192,128,65536,512,65536,512,65536,512,65536,512,
                       512,512,512,512,262144,2048,262144,512,8192,64,320,5};
  const int src[NE] = {0,1,4,5,6,7,8,9,10,11,12,13,14,15,16,17,18,19,20,21,22,23,24,
                       25,26,27,28,29,30,31,32,33,34,35,36,37,38,39,40,41,42,43,44};
  const int dst[NE] = {OFF_TS,OFF_TIMES,OFF_ENCW,OFF_ENCB,OFF_ENCG,OFF_ENCBETA,OFF_DW1,
                       OFF_DB1,OFF_DW2,OFF_DB2,OFF_DW3,OFF_DB3,OFF_AW1,OFF_AB1,OFF_AW2,
                       OFF_AB2,OFF_BW1,OFF_BB1,OFF_BW2,OFF_BB2,OFF_MD,OFF_INW,OFF_INB,
                       OFF_WQ,OFF_BQ,OFF_WK,OFF_BK,OFF_WV,OFF_BV,OFF_WO,OFF_BO,
                       OFF_LN1G,OFF_LN1B,OFF_LN2G,OFF_LN2B,OFF_FW1,OFF_FB1,OFF_FW2,
                       OFF_FB2,OFF_CW1,OFF_CB1,OFF_CW2,OFF_CB2};
  const unsigned* eg = (const unsigned*)pk.p[6];     // enc_g (all ones)
  int gmode = (eg[0] == 0x3F803F80u) ? 1 : 0;

  __shared__ int isbf[NE];
  if (threadIdx.x < NE) {
    int k = threadIdx.x;
    int f = gmode;
    if (gmode) {
      const unsigned short* us = (const unsigned short*)pk.p[src[k]];
      int n = cnt[k] < 32 ? cnt[k] : 32;
      for (int i = 0; i < n; ++i) {
        unsigned short h = us[i];
        if (h & 0x7FFF) {
          float a = fabsf(bfdec(h));
          if (!(a > 1e-20f && a < 1e4f)) { f = 0; break; }
        }
      }
    }
    isbf[k] = f;
  }
  __syncthreads();

  int gid = blockIdx.x * 256 + threadIdx.x;
  if (gid == 0) {
    int nf = gmode;
    if (gmode) {
      const unsigned short* us = (const unsigned short*)pk.p[2];
      for (int i = 0; i < 32; ++i) {
        unsigned short h = us[i];
        if (h & 0x7FFF) {
          float a = fabsf(bfdec(h));
          if (!(a > 1e-20f && a < 1e4f)) { nf = 0; break; }
        }
      }
    }
    ((int*)W)[OFF_FLAG] = nf;
  }

  const int TOT = 905350;
  int stride = gridDim.x * 256;
  for (int e = gid; e < TOT; e += stride) {
    int rem = e, k = 0;
    while (rem >= cnt[k]) { rem -= cnt[k]; ++k; }
    float v;
    if (isbf[k]) v = bfdec(((const unsigned short*)pk.p[src[k]])[rem]);
    else         v = ((const float*)pk.p[src[k]])[rem];
    W[dst[k] + rem] = v;
  }
}

// ---------------- encoder: enc = relu(LN(ts @ enc_w + enc_b)) ----------------
__global__ __launch_bounds__(64) void encoder_kernel(float* __restrict__ W,
                                                     float* __restrict__ outf) {
  int row = blockIdx.x;        // b*512 + s
  int j = threadIdx.x;
  float t0 = W[OFF_TS + row*3 + 0];
  float t1 = W[OFF_TS + row*3 + 1];
  float t2 = W[OFF_TS + row*3 + 2];
  float v = W[OFF_ENCB + j] + t0 * W[OFF_ENCW + j] + t1 * W[OFF_ENCW + 64 + j]
          + t2 * W[OFF_ENCW + 128 + j];
  float mean = wsum64(v) * (1.f / 64.f);
  float d = v - mean;
  float var = wsum64(d * d) * (1.f / 64.f);
  float o = d * rsqrtf(var + 1e-5f) * W[OFF_ENCG + j] + W[OFF_ENCBETA + j];
  o = fmaxf(o, 0.f);
  W[OFF_ENC + row*64 + j] = o;
  int s = row & 511;
  if (s % 51 == 0) {
    W[OFF_SDE + row*64 + j] = o;
    outf[160 + row*64 + j] = o;
  }
}

// ---------------- precompute A(t), Bt(t), bias1(t) ----------------
__global__ __launch_bounds__(128) void precompute_kernel(float* __restrict__ W) {
  int bi = blockIdx.x;             // 0..5109
  int step = bi / 10, k = bi - step * 10;
  float t_prev = W[OFF_TIMES + step];
  float t_cur  = W[OFF_TIMES + step + 1];
  float h = (t_cur - t_prev) * 0.1f;
  float t = t_prev + (float)k * h;
  __shared__ float av[64], bv[64];
  int tid = threadIdx.x;
  if (tid < 64) av[tid] = fast_tanh(t * W[OFF_AW1 + tid] + W[OFF_AB1 + tid]);
  else { int j = tid - 64; bv[j] = fast_tanh(t * W[OFF_BW1 + j] + W[OFF_BB1 + j]); }
  __syncthreads();
  if (tid < 64) {
    float a = W[OFF_AB2 + tid];
    for (int i = 0; i < 64; ++i) a += av[i] * W[OFF_AW2 + i*64 + tid];
    W[OFF_COEFA + bi*64 + tid] = fmaxf(a, 0.f) + log1pf(__expf(-fabsf(a)));
  } else {
    int j = tid - 64;
    float a = W[OFF_BB2 + j];
    for (int i = 0; i < 64; ++i) a += bv[i] * W[OFF_BW2 + i*64 + j];
    W[OFF_COEFB + bi*64 + j] = fast_tanh(a);
  }
  W[OFF_B1C + bi*128 + tid] = t * W[OFF_DW1 + 64*128 + tid] + W[OFF_DB1 + tid];
}

// ---------------- SDE integrator (MFMA): 22 blocks, 4 waves split N ----------------
// MFMA 16x16x32 bf16 layouts (gfx950, learn_hip-verified):
//   A[m=lane&15][k=(lane>>4)*8+j]   B[k=(lane>>4)*8+j][n=lane&15]
//   C/D[row=(lane>>4)*4+reg][col=lane&15]
__global__ __launch_bounds__(256) void sde_kernel(float* __restrict__ W,
                                                  const void* __restrict__ noise,
                                                  float* __restrict__ outf) {
  __shared__ short ybf[16 * 72];     // y bf16, [m][k] pitch 72 (2-way banks)
  __shared__ short h1bf[16 * 136];   // h1 bf16, pitch 136
  __shared__ short h2bf[16 * 72];    // h2 bf16, pitch 72

  const int tid = threadIdx.x;
  const int w   = tid >> 6;          // wave 0..3
  const int lane = tid & 63;
  const int q   = lane >> 4;         // quad
  const int lq  = lane & 15;
  const int g   = blockIdx.x >> 1;          // segment 0..10
  const int r0  = (blockIdx.x & 1) * 16;    // batch rows r0..r0+15

  const int nmode = ((const int*)W)[OFF_FLAG];
  const float md = fabsf(W[OFF_MD]);
  const unsigned short* nb16 = (const unsigned short*)noise;
  const float* nf32 = (const float*)noise;

  // ---- load persistent B-frags (weights) into registers ----
  const int ncol = w*16 + lq;        // this lane's y/h2/drift column
  short8 B1f[2][2];                  // [ktile][ctile]; h1 cols n = w*32 + ct*16 + lq
#pragma unroll
  for (int kt = 0; kt < 2; ++kt)
#pragma unroll
    for (int ct = 0; ct < 2; ++ct)
#pragma unroll
      for (int j = 0; j < 8; ++j)
        B1f[kt][ct][j] = f2bf(W[OFF_DW1 + (kt*32 + q*8 + j)*128 + w*32 + ct*16 + lq]);
  short8 B2f[4];                     // h2 col n = ncol
#pragma unroll
  for (int kt = 0; kt < 4; ++kt)
#pragma unroll
    for (int j = 0; j < 8; ++j)
      B2f[kt][j] = f2bf(W[OFF_DW2 + (kt*32 + q*8 + j)*64 + ncol]);
  short8 B3f[2];
#pragma unroll
  for (int kt = 0; kt < 2; ++kt)
#pragma unroll
    for (int j = 0; j < 8; ++j)
      B3f[kt][j] = f2bf(W[OFF_DW3 + (kt*32 + q*8 + j)*64 + ncol]);
  const float db2v = W[OFF_DB2 + ncol];
  const float db3v = W[OFF_DB3 + ncol];

  // ---- init y (fp32 master in registers, D-layout) ----
  float yreg[4];
#pragma unroll
  for (int r = 0; r < 4; ++r) {
    yreg[r] = W[OFF_ENC + ((r0 + q*4 + r)*512 + 51*g)*64 + ncol];
    ybf[(q*4 + r)*72 + ncol] = f2bf(yreg[r]);
  }
  __syncthreads();

  const int nsteps = (g == 10) ? 1 : 50;
  for (int m = 0; m < nsteps; ++m) {
    const int istep = 51*g + m;
    const float t_prev = W[OFF_TIMES + istep];
    const float t_cur  = W[OFF_TIMES + istep + 1];
    const float hstep = (t_cur - t_prev) * 0.1f;
    const float sqh = sqrtf(hstep);
    for (int k = 0; k < 10; ++k) {
      const int ci = istep*10 + k;
      // prefetch per-substep scalars (global, L2-hot)
      const float bias_a = W[OFF_B1C + ci*128 + w*32 + lq];
      const float bias_b = W[OFF_B1C + ci*128 + w*32 + 16 + lq];
      const float ca = W[OFF_COEFA + ci*64 + ncol];
      const float cb = W[OFF_COEFB + ci*64 + ncol];
      float dwv[4];
      {
        const int nb = (((istep + 1)*10 + k)*32 + r0 + q*4)*64 + ncol;
#pragma unroll
        for (int r = 0; r < 4; ++r)
          dwv[r] = nmode ? bfdec(nb16[nb + r*64]) : nf32[nb + r*64];
      }
      // ---- stage 1: h1 = tanh(y @ w1 + bias1(t)) ----
      {
        short8 a0 = *(const short8*)&ybf[lq*72 + q*8];
        short8 a1 = *(const short8*)&ybf[lq*72 + 32 + q*8];
        f32x4 c0 = {bias_a, bias_a, bias_a, bias_a};
        c0 = __builtin_amdgcn_mfma_f32_16x16x32_bf16(a0, B1f[0][0], c0, 0, 0, 0);
        c0 = __builtin_amdgcn_mfma_f32_16x16x32_bf16(a1, B1f[1][0], c0, 0, 0, 0);
        f32x4 c1 = {bias_b, bias_b, bias_b, bias_b};
        c1 = __builtin_amdgcn_mfma_f32_16x16x32_bf16(a0, B1f[0][1], c1, 0, 0, 0);
        c1 = __builtin_amdgcn_mfma_f32_16x16x32_bf16(a1, B1f[1][1], c1, 0, 0, 0);
#pragma unroll
        for (int r = 0; r < 4; ++r) {
          h1bf[(q*4 + r)*136 + w*32 + lq]      = f2bf(fast_tanh(c0[r]));
          h1bf[(q*4 + r)*136 + w*32 + 16 + lq] = f2bf(fast_tanh(c1[r]));
        }
      }
      __syncthreads();
      // ---- stage 2: h2 = tanh(h1 @ w2 + db2) ----
      {
        f32x4 d2 = {db2v, db2v, db2v, db2v};
#pragma unroll
        for (int kt = 0; kt < 4; ++kt) {
          short8 a = *(const short8*)&h1bf[lq*136 + kt*32 + q*8];
          d2 = __builtin_amdgcn_mfma_f32_16x16x32_bf16(a, B2f[kt], d2, 0, 0, 0);
        }
#pragma unroll
        for (int r = 0; r < 4; ++r)
          h2bf[(q*4 + r)*72 + ncol] = f2bf(fast_tanh(d2[r]));
      }
      __syncthreads();
      // ---- stage 3: drift = h2 @ w3 + db3; Euler-Maruyama update ----
      {
        f32x4 d3 = {db3v, db3v, db3v, db3v};
#pragma unroll
        for (int kt = 0; kt < 2; ++kt) {
          short8 a = *(const short8*)&h2bf[lq*72 + kt*32 + q*8];
          d3 = __builtin_amdgcn_mfma_f32_16x16x32_bf16(a, B3f[kt], d3, 0, 0, 0);
        }
#pragma unroll
        for (int r = 0; r < 4; ++r) {
          float yv = yreg[r];
          yv = yv + d3[r]*hstep + (ca + cb*yv + md)*sqh*dwv[r];
          yreg[r] = yv;
          ybf[(q*4 + r)*72 + ncol] = f2bf(yv);
        }
      }
      __syncthreads();
    }
    // write sde_features[:, istep+1]
#pragma unroll
    for (int r = 0; r < 4; ++r) {
      const int gi = ((r0 + q*4 + r)*512 + (istep + 1))*64 + ncol;
      W[OFF_SDE + gi] = yreg[r];
      outf[160 + gi] = yreg[r];
    }
  }
}

// ---------------- generic fp32 GEMM: C = act(A[MxK] @ B[KxN] + bias) ----------------
__global__ __launch_bounds__(256) void gemm_kernel(const float* __restrict__ A,
    const float* __restrict__ Bm, const float* __restrict__ bias,
    float* __restrict__ C, int M, int N, int K, int act) {
  __shared__ float As[16][68];   // [kk][m], padded
  __shared__ float Bs[16][64];
  int bm = blockIdx.x * 64, bn = blockIdx.y * 64;
  int tid = threadIdx.x;
  int tm = tid >> 4, tn = tid & 15;
  int aRow = tid >> 2, aK = (tid & 3) * 4;
  int bK = tid >> 4, bN = (tid & 15) * 4;
  float acc[4][4];
#pragma unroll
  for (int i = 0; i < 4; ++i)
#pragma unroll
    for (int j = 0; j < 4; ++j) acc[i][j] = 0.f;
  for (int k0 = 0; k0 < K; k0 += 16) {
    __syncthreads();
    float4 av = *(const float4*)&A[(bm + aRow)*K + k0 + aK];
    As[aK + 0][aRow] = av.x; As[aK + 1][aRow] = av.y;
    As[aK + 2][aRow] = av.z; As[aK + 3][aRow] = av.w;
    *(float4*)&Bs[bK][bN] = *(const float4*)&Bm[(k0 + bK)*N + bn + bN];
    __syncthreads();
#pragma unroll
    for (int kk = 0; kk < 16; ++kk) {
      float4 a  = *(const float4*)&As[kk][tm*4];
      float4 bv = *(const float4*)&Bs[kk][tn*4];
      acc[0][0] += a.x*bv.x; acc[0][1] += a.x*bv.y; acc[0][2] += a.x*bv.z; acc[0][3] += a.x*bv.w;
      acc[1][0] += a.y*bv.x; acc[1][1] += a.y*bv.y; acc[1][2] += a.y*bv.z; acc[1][3] += a.y*bv.w;
      acc[2][0] += a.z*bv.x; acc[2][1] += a.z*bv.y; acc[2][2] += a.z*bv.z; acc[2][3] += a.z*bv.w;
      acc[3][0] += a.w*bv.x; acc[3][1] += a.w*bv.y; acc[3][2] += a.w*bv.z; acc[3][3] += a.w*bv.w;
    }
  }
  float4 bb = *(const float4*)&bias[bn + tn*4];
#pragma unroll
  for (int i = 0; i < 4; ++i) {
    int row = bm + tm*4 + i;
    float4 v;
    v.x = acc[i][0] + bb.x; v.y = acc[i][1] + bb.y;
    v.z = acc[i][2] + bb.z; v.w = acc[i][3] + bb.w;
    if (act) { v.x = fmaxf(v.x, 0.f); v.y = fmaxf(v.y, 0.f);
               v.z = fmaxf(v.z, 0.f); v.w = fmaxf(v.w, 0.f); }
    *(float4*)&C[row*N + bn + tn*4] = v;
  }
}

// ---------------- flash-style attention, DH=16, one wave per 64 q-rows ----------------
__global__ __launch_bounds__(64) void attn_kernel(const float* __restrict__ Q,
    const float* __restrict__ K, const float* __restrict__ V, float* __restrict__ O) {
  int blk = blockIdx.x;
  int qt = blk & 7;
  int h  = (blk >> 3) & 7;
  int b  = blk >> 6;
  int tid = threadIdx.x;
  int qrow = b*512 + qt*64 + tid;
  int col0 = h*16;
  float q[16], o[16];
#pragma unroll
  for (int d = 0; d < 16; ++d) { q[d] = Q[qrow*128 + col0 + d]; o[d] = 0.f; }
  float mM = -1e30f, lsum = 0.f;
  __shared__ float kv[64][16];
  __shared__ float vv[64][16];
  for (int kt = 0; kt < 8; ++kt) {
    __syncthreads();
    int krow = b*512 + kt*64 + tid;
#pragma unroll
    for (int d4 = 0; d4 < 4; ++d4) {
      *(float4*)&kv[tid][d4*4] = *(const float4*)&K[krow*128 + col0 + d4*4];
      *(float4*)&vv[tid][d4*4] = *(const float4*)&V[krow*128 + col0 + d4*4];
    }
    __syncthreads();
    float s[64];
    float tmax = -1e30f;
#pragma unroll
    for (int c = 0; c < 64; ++c) {
      float a = 0.f;
#pragma unroll
      for (int d = 0; d < 16; ++d) a += q[d]*kv[c][d];
      a *= 0.25f;       // 1/sqrt(DH)
      s[c] = a;
      tmax = fmaxf(tmax, a);
    }
    float mNew = fmaxf(mM, tmax);
    float alpha = __expf(mM - mNew);
    lsum *= alpha;
#pragma unroll
    for (int d = 0; d < 16; ++d) o[d] *= alpha;
#pragma unroll
    for (int c = 0; c < 64; ++c) {
      float p = __expf(s[c] - mNew);
      lsum += p;
#pragma unroll
      for (int d = 0; d < 16; ++d) o[d] += p*vv[c][d];
    }
    mM = mNew;
  }
  float inv = 1.f / lsum;
#pragma unroll
  for (int d = 0; d < 16; ++d) O[qrow*128 + col0 + d] = o[d]*inv;
}

// ---------------- residual + LayerNorm (D=128) ----------------
__global__ __launch_bounds__(128) void resln_kernel(float* __restrict__ x,
    const float* __restrict__ r, const float* __restrict__ g, const float* __restrict__ bta) {
  int row = blockIdx.x, j = threadIdx.x;
  int idx = row*128 + j;
  float v = x[idx] + r[idx];
  __shared__ float sm[2], sv[2];
  float s = wsum64(v);
  if ((j & 63) == 0) sm[j >> 6] = s;
  __syncthreads();
  float mean = (sm[0] + sm[1]) * (1.f / 128.f);
  float d = v - mean;
  float qq = wsum64(d * d);
  if ((j & 63) == 0) sv[j >> 6] = qq;
  __syncthreads();
  float var = (sv[0] + sv[1]) * (1.f / 128.f);
  x[idx] = d * rsqrtf(var + 1e-5f) * g[j] + bta[j];
}

// ---------------- mean-pool + 2-layer classifier ----------------
__global__ __launch_bounds__(128) void pool_cls_kernel(const float* __restrict__ W,
                                                       float* __restrict__ outf) {
  int b = blockIdx.x, j = threadIdx.x;
  float s = 0.f;
  for (int ss = 0; ss < 512; ++ss) s += W[OFF_X + ((b*512 + ss)*128) + j];
  __shared__ float pooled[128];
  __shared__ float hid[64];
  pooled[j] = s * (1.f / 512.f);
  __syncthreads();
  if (j < 64) {
    float a = W[OFF_CB1 + j];
    for (int i = 0; i < 128; ++i) a += pooled[i] * W[OFF_CW1 + i*64 + j];
    hid[j] = fmaxf(a, 0.f);
  }
  __syncthreads();
  if (j < 5) {
    float a = W[OFF_CB2 + j];
    for (int i = 0; i < 64; ++i) a += hid[i] * W[OFF_CW2 + i*5 + j];
    outf[b*5 + j] = a;
  }
}

// ---------------- launch ----------------
extern "C" void kernel_launch(void* const* d_in, const int* in_sizes, int n_in,
                              void* d_out, int out_size, void* d_ws, size_t ws_size,
                              hipStream_t stream) {
  (void)in_sizes; (void)out_size; (void)ws_size;
  float* W = reinterpret_cast<float*>(d_ws);
  float* outf = reinterpret_cast<float*>(d_out);
  PtrPack pk;
  for (int i = 0; i < 45 && i < n_in; ++i) pk.p[i] = d_in[i];

  ingest_kernel<<<512, 256, 0, stream>>>(pk, W);
  encoder_kernel<<<16384, 64, 0, stream>>>(W, outf);
  precompute_kernel<<<5110, 128, 0, stream>>>(W);
  sde_kernel<<<22, 256, 0, stream>>>(W, d_in[2], outf);

  // x = sde_features @ in_w + in_b
  gemm_kernel<<<dim3(256, 2), 256, 0, stream>>>(W + OFF_SDE, W + OFF_INW, W + OFF_INB,
                                                W + OFF_X, 16384, 128, 64, 0);
  for (int l = 0; l < 4; ++l) {
    gemm_kernel<<<dim3(256, 2), 256, 0, stream>>>(W + OFF_X, W + OFF_WQ + l*16384,
        W + OFF_BQ + l*128, W + OFF_QB, 16384, 128, 128, 0);
    gemm_kernel<<<dim3(256, 2), 256, 0, stream>>>(W + OFF_X, W + OFF_WK + l*16384,
        W + OFF_BK + l*128, W + OFF_KB, 16384, 128, 128, 0);
    gemm_kernel<<<dim3(256, 2), 256, 0, stream>>>(W + OFF_X, W + OFF_WV + l*16384,
        W + OFF_BV + l*128, W + OFF_VB, 16384, 128, 128, 0);
    attn_kernel<<<2048, 64, 0, stream>>>(W + OFF_QB, W + OFF_KB, W + OFF_VB, W + OFF_OB);
    gemm_kernel<<<dim3(256, 2), 256, 0, stream>>>(W + OFF_OB, W + OFF_WO + l*16384,
        W + OFF_BO + l*128, W + OFF_TMP, 16384, 128, 128, 0);
    resln_kernel<<<16384, 128, 0, stream>>>(W + OFF_X, W + OFF_TMP,
        W + OFF_LN1G + l*128, W + OFF_LN1B + l*128);
    gemm_kernel<<<dim3(256, 8), 256, 0, stream>>>(W + OFF_X, W + OFF_FW1 + l*65536,
        W + OFF_FB1 + l*512, W + OFF_HB, 16384, 512, 128, 1);
    gemm_kernel<<<dim3(256, 2), 256, 0, stream>>>(W + OFF_HB, W + OFF_FW2 + l*65536,
        W + OFF_FB2 + l*128, W + OFF_TMP, 16384, 128, 512, 0);
    resln_kernel<<<16384, 128, 0, stream>>>(W + OFF_X, W + OFF_TMP,
        W + OFF_LN2G + l*128, W + OFF_LN2B + l*128);
  }
  pool_cls_kernel<<<32, 128, 0, stream>>>(W, outf);
}

// Round 4
// 1897.190 us; speedup vs baseline: 2.5480x; 1.1209x over previous
//
#include <hip/hip_runtime.h>
#include <hip/hip_bf16.h>

// ============================================================
// B=32, S=512, IN=3, H=64, D=128, NH=8, DH=16, L=4, C=5
// NSUB=10, MAX_CONSEC=50 -> SDE splits into 11 independent
// segments (state resets to enc at s % 51 == 0).
// Outputs (fp32): logits (160) then sde_features (32*512*64).
// R4: transformer GEMMs -> bf16 MFMA (16x16x32), QKV fused,
// bf16 activation buffers, weights pre-transposed to N-major.
// ============================================================

typedef __attribute__((ext_vector_type(8))) short short8;
typedef __attribute__((ext_vector_type(4))) float f32x4;

// ---------------- ws layout (float element offsets) ----------------
static constexpr int OFF_TS      = 0;         // 49152
static constexpr int OFF_TIMES   = 49152;     // 16384
static constexpr int OFF_ENCW    = 65536;     // 192
static constexpr int OFF_ENCB    = 65728;     // 64
static constexpr int OFF_ENCG    = 65792;     // 64
static constexpr int OFF_ENCBETA = 65856;     // 64
static constexpr int OFF_DW1     = 65920;     // 8320 (65x128)
static constexpr int OFF_DB1     = 74240;     // 128
static constexpr int OFF_DW2     = 74368;     // 8192 (128x64)
static constexpr int OFF_DB2     = 82560;     // 64
static constexpr int OFF_DW3     = 82624;     // 4096 (64x64)
static constexpr int OFF_DB3     = 86720;     // 64
static constexpr int OFF_AW1     = 86784;     // 64
static constexpr int OFF_AB1     = 86848;     // 64
static constexpr int OFF_AW2     = 86912;     // 4096
static constexpr int OFF_AB2     = 91008;     // 64
static constexpr int OFF_BW1     = 91072;     // 64
static constexpr int OFF_BB1     = 91136;     // 64
static constexpr int OFF_BW2     = 91200;     // 4096
static constexpr int OFF_BB2     = 95296;     // 64
static constexpr int OFF_MD      = 95360;     // 1
static constexpr int OFF_INW     = 95424;     // 8192 (64x128)
static constexpr int OFF_INB     = 103616;    // 128
static constexpr int OFF_WQ      = 103744;    // 4*128*128
static constexpr int OFF_BQ      = 169280;    // 4*128
static constexpr int OFF_WK      = 169792;
static constexpr int OFF_BK      = 235328;
static constexpr int OFF_WV      = 235840;
static constexpr int OFF_BV      = 301376;
static constexpr int OFF_WO      = 301888;
static constexpr int OFF_BO      = 367424;
static constexpr int OFF_LN1G    = 367936;    // 4*128
static constexpr int OFF_LN1B    = 368448;
static constexpr int OFF_LN2G    = 368960;
static constexpr int OFF_LN2B    = 369472;
static constexpr int OFF_FW1     = 369984;    // 4*128*512
static constexpr int OFF_FB1     = 632128;    // 4*512
static constexpr int OFF_FW2     = 634176;    // 4*512*128
static constexpr int OFF_FB2     = 896320;    // 4*128
static constexpr int OFF_CW1     = 896832;    // 128*64
static constexpr int OFF_CB1     = 905024;    // 64
static constexpr int OFF_CW2     = 905088;    // 64*5 (pad)
static constexpr int OFF_CB2     = 905472;    // 5 (pad)
static constexpr int OFF_FLAG    = 905536;    // int flag: 1 = noise is bf16
// compute buffers
static constexpr int OFF_ENC     = 905600;    // 32*512*64 fp32
static constexpr int OFF_COEFA   = 3002752;   // 5110*64
static constexpr int OFF_COEFB   = 3329792;   // 5110*64
static constexpr int OFF_B1C     = 3656832;   // 5110*128
static constexpr int OFF_X       = 4310912;   // 16384*128 fp32 (residual master)
// bf16 buffers (reusing the old fp32 Q/K/V/O/H region)
static constexpr int OFF_XBF     = 6408064;   // 16384*128 bf16 (1048576 f)
static constexpr int OFF_QKVBF   = 7456640;   // 16384*384 bf16 (3145728 f)
static constexpr int OFF_OBF     = 10602368;  // 16384*128 bf16
static constexpr int OFF_HBF     = 11650944;  // 16384*512 bf16 (4194304 f)
static constexpr int OFF_SDEBF   = 15845248;  // 16384*64 bf16 (524288 f)
static constexpr int OFF_WQKVT   = 16369536;  // 4*384*128 bf16 (98304 f)
static constexpr int OFF_WOT     = 16467840;  // 4*128*128 bf16 (32768 f)
static constexpr int OFF_FW1T    = 16500608;  // 4*512*128 bf16 (131072 f)
static constexpr int OFF_FW2T    = 16631680;  // 4*128*512 bf16 (131072 f)
static constexpr int OFF_INWT    = 16762752;  // 128*64 bf16 (4096 f)
static constexpr int OFF_BQKV    = 16766848;  // 4*384 fp32
static constexpr int OFF_TMP     = 23185280;  // 16384*128 fp32
// total = 25282432 floats ~= 96.5 MiB (unchanged from R2/R3)

struct PtrPack { const void* p[45]; };

// ---------------- helpers ----------------
__device__ inline float wsum64(float v) {
#pragma unroll
  for (int off = 32; off > 0; off >>= 1) v += __shfl_xor(v, off, 64);
  return v;
}

__device__ inline float fast_tanh(float x) {
  x = fminf(fmaxf(x, -15.f), 15.f);
  float e = __expf(2.f * x);
  return (e - 1.f) / (e + 1.f);
}

__device__ inline float bfdec(unsigned short h) {
  return __uint_as_float(((unsigned)h) << 16);
}

// round-to-nearest-even f32 -> bf16 bits
__device__ inline short f2bf(float f) {
  unsigned u = __float_as_uint(f);
  return (short)((u + 0x7FFFu + ((u >> 16) & 1u)) >> 16);
}

// ---------------- ingest: convert all float inputs to f32 mirrors ----------------
__global__ __launch_bounds__(256) void ingest_kernel(PtrPack pk, float* __restrict__ W) {
  const int NE = 43;
  const int cnt[NE] = {49152,16384,192,64,64,64,8320,128,8192,64,4096,64,64,64,4096,64,
                       64,64,4096,64,1,8192,128,65536,512,65536,512,65536,512,65536,512,
                       512,512,512,512,262144,2048,262144,512,8192,64,320,5};
  const int src[NE] = {0,1,4,5,6,7,8,9,10,11,12,13,14,15,16,17,18,19,20,21,22,23,24,
                       25,26,27,28,29,30,31,32,33,34,35,36,37,38,39,40,41,42,43,44};
  const int dst[NE] = {OFF_TS,OFF_TIMES,OFF_ENCW,OFF_ENCB,OFF_ENCG,OFF_ENCBETA,OFF_DW1,
                       OFF_DB1,OFF_DW2,OFF_DB2,OFF_DW3,OFF_DB3,OFF_AW1,OFF_AB1,OFF_AW2,
                       OFF_AB2,OFF_BW1,OFF_BB1,OFF_BW2,OFF_BB2,OFF_MD,OFF_INW,OFF_INB,
                       OFF_WQ,OFF_BQ,OFF_WK,OFF_BK,OFF_WV,OFF_BV,OFF_WO,OFF_BO,
                       OFF_LN1G,OFF_LN1B,OFF_LN2G,OFF_LN2B,OFF_FW1,OFF_FB1,OFF_FW2,
                       OFF_FB2,OFF_CW1,OFF_CB1,OFF_CW2,OFF_CB2};
  const unsigned* eg = (const unsigned*)pk.p[6];     // enc_g (all ones)
  int gmode = (eg[0] == 0x3F803F80u) ? 1 : 0;

  __shared__ int isbf[NE];
  if (threadIdx.x < NE) {
    int k = threadIdx.x;
    int f = gmode;
    if (gmode) {
      const unsigned short* us = (const unsigned short*)pk.p[src[k]];
      int n = cnt[k] < 32 ? cnt[k] : 32;
      for (int i = 0; i < n; ++i) {
        unsigned short h = us[i];
        if (h & 0x7FFF) {
          float a = fabsf(bfdec(h));
          if (!(a > 1e-20f && a < 1e4f)) { f = 0; break; }
        }
      }
    }
    isbf[k] = f;
  }
  __syncthreads();

  int gid = blockIdx.x * 256 + threadIdx.x;
  if (gid == 0) {
    int nf = gmode;
    if (gmode) {
      const unsigned short* us = (const unsigned short*)pk.p[2];
      for (int i = 0; i < 32; ++i) {
        unsigned short h = us[i];
        if (h & 0x7FFF) {
          float a = fabsf(bfdec(h));
          if (!(a > 1e-20f && a < 1e4f)) { nf = 0; break; }
        }
      }
    }
    ((int*)W)[OFF_FLAG] = nf;
  }

  const int TOT = 905350;
  int stride = gridDim.x * 256;
  for (int e = gid; e < TOT; e += stride) {
    int rem = e, k = 0;
    while (rem >= cnt[k]) { rem -= cnt[k]; ++k; }
    float v;
    if (isbf[k]) v = bfdec(((const unsigned short*)pk.p[src[k]])[rem]);
    else         v = ((const float*)pk.p[src[k]])[rem];
    W[dst[k] + rem] = v;
  }
}

// ---------------- prep: transpose transformer weights to bf16 N-major ----------------
__global__ __launch_bounds__(256) void prep_kernel(float* __restrict__ W) {
  short* wqkvT = (short*)(W + OFF_WQKVT);
  short* woT   = (short*)(W + OFF_WOT);
  short* fw1T  = (short*)(W + OFF_FW1T);
  short* fw2T  = (short*)(W + OFF_FW2T);
  short* inwT  = (short*)(W + OFF_INWT);
  float* bqkv  = W + OFF_BQKV;
  int gid = blockIdx.x * 256 + threadIdx.x;
  int stride = gridDim.x * 256;
  for (int e = gid; e < 796160; e += stride) {
    if (e < 196608) {            // wqkvT[l][384][128]
      int l = e / 49152, r = e % 49152, n = r >> 7, k = r & 127;
      float v = (n < 128) ? W[OFF_WQ + l*16384 + k*128 + n]
              : (n < 256) ? W[OFF_WK + l*16384 + k*128 + (n - 128)]
                          : W[OFF_WV + l*16384 + k*128 + (n - 256)];
      wqkvT[e] = f2bf(v);
    } else if (e < 262144) {     // woT[l][128][128]
      int t = e - 196608; int l = t / 16384, r = t % 16384, n = r >> 7, k = r & 127;
      woT[t] = f2bf(W[OFF_WO + l*16384 + k*128 + n]);
    } else if (e < 524288) {     // fw1T[l][512][128]
      int t = e - 262144; int l = t / 65536, r = t % 65536, n = r >> 7, k = r & 127;
      fw1T[t] = f2bf(W[OFF_FW1 + l*65536 + k*512 + n]);
    } else if (e < 786432) {     // fw2T[l][128][512]
      int t = e - 524288; int l = t / 65536, r = t % 65536, n = r >> 9, k = r & 511;
      fw2T[t] = f2bf(W[OFF_FW2 + l*65536 + k*128 + n]);
    } else if (e < 794624) {     // inwT[128][64]
      int t = e - 786432; int n = t >> 6, k = t & 63;
      inwT[t] = f2bf(W[OFF_INW + k*128 + n]);
    } else {                     // bqkv[4][384] fp32
      int t = e - 794624; int l = t / 384, j = t % 384;
      bqkv[t] = (j < 128) ? W[OFF_BQ + l*128 + j]
              : (j < 256) ? W[OFF_BK + l*128 + (j - 128)]
                          : W[OFF_BV + l*128 + (j - 256)];
    }
  }
}

// ---------------- encoder: enc = relu(LN(ts @ enc_w + enc_b)) ----------------
__global__ __launch_bounds__(64) void encoder_kernel(float* __restrict__ W,
                                                     float* __restrict__ outf) {
  int row = blockIdx.x;        // b*512 + s
  int j = threadIdx.x;
  float t0 = W[OFF_TS + row*3 + 0];
  float t1 = W[OFF_TS + row*3 + 1];
  float t2 = W[OFF_TS + row*3 + 2];
  float v = W[OFF_ENCB + j] + t0 * W[OFF_ENCW + j] + t1 * W[OFF_ENCW + 64 + j]
          + t2 * W[OFF_ENCW + 128 + j];
  float mean = wsum64(v) * (1.f / 64.f);
  float d = v - mean;
  float var = wsum64(d * d) * (1.f / 64.f);
  float o = d * rsqrtf(var + 1e-5f) * W[OFF_ENCG + j] + W[OFF_ENCBETA + j];
  o = fmaxf(o, 0.f);
  W[OFF_ENC + row*64 + j] = o;
  int s = row & 511;
  if (s % 51 == 0) {           // reset positions: sde_features[:,s] = enc[:,s]
    ((short*)(W + OFF_SDEBF))[row*64 + j] = f2bf(o);
    outf[160 + row*64 + j] = o;
  }
}

// ---------------- precompute A(t), Bt(t), bias1(t) ----------------
__global__ __launch_bounds__(128) void precompute_kernel(float* __restrict__ W) {
  int bi = blockIdx.x;             // 0..5109
  int step = bi / 10, k = bi - step * 10;
  float t_prev = W[OFF_TIMES + step];
  float t_cur  = W[OFF_TIMES + step + 1];
  float h = (t_cur - t_prev) * 0.1f;
  float t = t_prev + (float)k * h;
  __shared__ float av[64], bv[64];
  int tid = threadIdx.x;
  if (tid < 64) av[tid] = fast_tanh(t * W[OFF_AW1 + tid] + W[OFF_AB1 + tid]);
  else { int j = tid - 64; bv[j] = fast_tanh(t * W[OFF_BW1 + j] + W[OFF_BB1 + j]); }
  __syncthreads();
  if (tid < 64) {
    float a = W[OFF_AB2 + tid];
    for (int i = 0; i < 64; ++i) a += av[i] * W[OFF_AW2 + i*64 + tid];
    W[OFF_COEFA + bi*64 + tid] = fmaxf(a, 0.f) + log1pf(__expf(-fabsf(a)));
  } else {
    int j = tid - 64;
    float a = W[OFF_BB2 + j];
    for (int i = 0; i < 64; ++i) a += bv[i] * W[OFF_BW2 + i*64 + j];
    W[OFF_COEFB + bi*64 + j] = fast_tanh(a);
  }
  W[OFF_B1C + bi*128 + tid] = t * W[OFF_DW1 + 64*128 + tid] + W[OFF_DB1 + tid];
}

// ---------------- SDE integrator (MFMA): 22 blocks, 4 waves split N ----------------
// MFMA 16x16x32 bf16 layouts (gfx950, learn_hip-verified):
//   A[m=lane&15][k=(lane>>4)*8+j]   B[k=(lane>>4)*8+j][n=lane&15]
//   C/D[row=(lane>>4)*4+reg][col=lane&15]
__global__ __launch_bounds__(256) void sde_kernel(float* __restrict__ W,
                                                  const void* __restrict__ noise,
                                                  float* __restrict__ outf) {
  __shared__ short ybf[16 * 72];     // y bf16, [m][k] pitch 72
  __shared__ short h1bf[16 * 136];   // h1 bf16, pitch 136
  __shared__ short h2bf[16 * 72];    // h2 bf16, pitch 72

  const int tid = threadIdx.x;
  const int w   = tid >> 6;          // wave 0..3
  const int lane = tid & 63;
  const int q   = lane >> 4;         // quad
  const int lq  = lane & 15;
  const int g   = blockIdx.x >> 1;          // segment 0..10
  const int r0  = (blockIdx.x & 1) * 16;    // batch rows r0..r0+15

  const int nmode = ((const int*)W)[OFF_FLAG];
  const float md = fabsf(W[OFF_MD]);
  const unsigned short* nb16 = (const unsigned short*)noise;
  const float* nf32 = (const float*)noise;
  short* sdebf = (short*)(W + OFF_SDEBF);

  // ---- load persistent B-frags (weights) into registers ----
  const int ncol = w*16 + lq;        // this lane's y/h2/drift column
  short8 B1f[2][2];                  // [ktile][ctile]; h1 cols n = w*32 + ct*16 + lq
#pragma unroll
  for (int kt = 0; kt < 2; ++kt)
#pragma unroll
    for (int ct = 0; ct < 2; ++ct)
#pragma unroll
      for (int j = 0; j < 8; ++j)
        B1f[kt][ct][j] = f2bf(W[OFF_DW1 + (kt*32 + q*8 + j)*128 + w*32 + ct*16 + lq]);
  short8 B2f[4];                     // h2 col n = ncol
#pragma unroll
  for (int kt = 0; kt < 4; ++kt)
#pragma unroll
    for (int j = 0; j < 8; ++j)
      B2f[kt][j] = f2bf(W[OFF_DW2 + (kt*32 + q*8 + j)*64 + ncol]);
  short8 B3f[2];
#pragma unroll
  for (int kt = 0; kt < 2; ++kt)
#pragma unroll
    for (int j = 0; j < 8; ++j)
      B3f[kt][j] = f2bf(W[OFF_DW3 + (kt*32 + q*8 + j)*64 + ncol]);
  const float db2v = W[OFF_DB2 + ncol];
  const float db3v = W[OFF_DB3 + ncol];

  // ---- init y (fp32 master in registers, D-layout) ----
  float yreg[4];
#pragma unroll
  for (int r = 0; r < 4; ++r) {
    yreg[r] = W[OFF_ENC + ((r0 + q*4 + r)*512 + 51*g)*64 + ncol];
    ybf[(q*4 + r)*72 + ncol] = f2bf(yreg[r]);
  }
  __syncthreads();

  const int nsteps = (g == 10) ? 1 : 50;
  for (int m = 0; m < nsteps; ++m) {
    const int istep = 51*g + m;
    const float t_prev = W[OFF_TIMES + istep];
    const float t_cur  = W[OFF_TIMES + istep + 1];
    const float hstep = (t_cur - t_prev) * 0.1f;
    const float sqh = sqrtf(hstep);
    for (int k = 0; k < 10; ++k) {
      const int ci = istep*10 + k;
      const float bias_a = W[OFF_B1C + ci*128 + w*32 + lq];
      const float bias_b = W[OFF_B1C + ci*128 + w*32 + 16 + lq];
      const float ca = W[OFF_COEFA + ci*64 + ncol];
      const float cb = W[OFF_COEFB + ci*64 + ncol];
      float dwv[4];
      {
        const int nb = (((istep + 1)*10 + k)*32 + r0 + q*4)*64 + ncol;
#pragma unroll
        for (int r = 0; r < 4; ++r)
          dwv[r] = nmode ? bfdec(nb16[nb + r*64]) : nf32[nb + r*64];
      }
      // ---- stage 1: h1 = tanh(y @ w1 + bias1(t)) ----
      {
        short8 a0 = *(const short8*)&ybf[lq*72 + q*8];
        short8 a1 = *(const short8*)&ybf[lq*72 + 32 + q*8];
        f32x4 c0 = {bias_a, bias_a, bias_a, bias_a};
        c0 = __builtin_amdgcn_mfma_f32_16x16x32_bf16(a0, B1f[0][0], c0, 0, 0, 0);
        c0 = __builtin_amdgcn_mfma_f32_16x16x32_bf16(a1, B1f[1][0], c0, 0, 0, 0);
        f32x4 c1 = {bias_b, bias_b, bias_b, bias_b};
        c1 = __builtin_amdgcn_mfma_f32_16x16x32_bf16(a0, B1f[0][1], c1, 0, 0, 0);
        c1 = __builtin_amdgcn_mfma_f32_16x16x32_bf16(a1, B1f[1][1], c1, 0, 0, 0);
#pragma unroll
        for (int r = 0; r < 4; ++r) {
          h1bf[(q*4 + r)*136 + w*32 + lq]      = f2bf(fast_tanh(c0[r]));
          h1bf[(q*4 + r)*136 + w*32 + 16 + lq] = f2bf(fast_tanh(c1[r]));
        }
      }
      __syncthreads();
      // ---- stage 2: h2 = tanh(h1 @ w2 + db2) ----
      {
        f32x4 d2 = {db2v, db2v, db2v, db2v};
#pragma unroll
        for (int kt = 0; kt < 4; ++kt) {
          short8 a = *(const short8*)&h1bf[lq*136 + kt*32 + q*8];
          d2 = __builtin_amdgcn_mfma_f32_16x16x32_bf16(a, B2f[kt], d2, 0, 0, 0);
        }
#pragma unroll
        for (int r = 0; r < 4; ++r)
          h2bf[(q*4 + r)*72 + ncol] = f2bf(fast_tanh(d2[r]));
      }
      __syncthreads();
      // ---- stage 3: drift = h2 @ w3 + db3; Euler-Maruyama update ----
      {
        f32x4 d3 = {db3v, db3v, db3v, db3v};
#pragma unroll
        for (int kt = 0; kt < 2; ++kt) {
          short8 a = *(const short8*)&h2bf[lq*72 + kt*32 + q*8];
          d3 = __builtin_amdgcn_mfma_f32_16x16x32_bf16(a, B3f[kt], d3, 0, 0, 0);
        }
#pragma unroll
        for (int r = 0; r < 4; ++r) {
          float yv = yreg[r];
          yv = yv + d3[r]*hstep + (ca + cb*yv + md)*sqh*dwv[r];
          yreg[r] = yv;
          ybf[(q*4 + r)*72 + ncol] = f2bf(yv);
        }
      }
      __syncthreads();
    }
    // write sde_features[:, istep+1]
#pragma unroll
    for (int r = 0; r < 4; ++r) {
      const int gi = ((r0 + q*4 + r)*512 + (istep + 1))*64 + ncol;
      sdebf[gi] = f2bf(yreg[r]);
      outf[160 + gi] = yreg[r];
    }
  }
}

// ---------------- bf16 MFMA GEMM: C = act(A[Mx K] @ B + bias) ----------------
// A: bf16 row-major [M][K]; BT: bf16 [N][K] (B transposed); out fp32 and/or bf16.
// Tile 128x128, 4 waves in 2x2, each wave 64x64 via 4x4 MFMA 16x16x32 tiles.
__global__ __launch_bounds__(256) void gemm_bf16_kernel(
    const short* __restrict__ A, const short* __restrict__ BT,
    const float* __restrict__ bias, float* __restrict__ Cf,
    short* __restrict__ Cb, int N, int K, int relu) {
  __shared__ short As[128 * 40];   // pitch 40 (pad 8)
  __shared__ short Bs[128 * 40];
  const int tid = threadIdx.x;
  const int w = tid >> 6, lane = tid & 63, q = lane >> 4, lq = lane & 15;
  const int wm = (w >> 1) * 64, wn = (w & 1) * 64;
  const int bm = blockIdx.x * 128, bn = blockIdx.y * 128;
  const int arow = tid >> 1, ah = (tid & 1) * 16;
  f32x4 acc[4][4];
#pragma unroll
  for (int i = 0; i < 4; ++i)
#pragma unroll
    for (int j = 0; j < 4; ++j) acc[i][j] = (f32x4){0.f, 0.f, 0.f, 0.f};

  for (int k0 = 0; k0 < K; k0 += 32) {
    // prefetch into regs (overlaps previous MFMA phase)
    short8 a0 = *(const short8*)&A[(bm + arow)*K + k0 + ah];
    short8 a1 = *(const short8*)&A[(bm + arow)*K + k0 + ah + 8];
    short8 b0 = *(const short8*)&BT[(bn + arow)*K + k0 + ah];
    short8 b1 = *(const short8*)&BT[(bn + arow)*K + k0 + ah + 8];
    __syncthreads();   // previous iteration's LDS reads done
    *(short8*)&As[arow*40 + ah]     = a0;
    *(short8*)&As[arow*40 + ah + 8] = a1;
    *(short8*)&Bs[arow*40 + ah]     = b0;
    *(short8*)&Bs[arow*40 + ah + 8] = b1;
    __syncthreads();
    short8 af[4], bf[4];
#pragma unroll
    for (int mi = 0; mi < 4; ++mi)
      af[mi] = *(const short8*)&As[(wm + mi*16 + lq)*40 + q*8];
#pragma unroll
    for (int ni = 0; ni < 4; ++ni)
      bf[ni] = *(const short8*)&Bs[(wn + ni*16 + lq)*40 + q*8];
#pragma unroll
    for (int mi = 0; mi < 4; ++mi)
#pragma unroll
      for (int ni = 0; ni < 4; ++ni)
        acc[mi][ni] = __builtin_amdgcn_mfma_f32_16x16x32_bf16(af[mi], bf[ni],
                                                              acc[mi][ni], 0, 0, 0);
  }
  // epilogue: lane holds D[row=q*4+r][col=lq] per 16x16 tile
#pragma unroll
  for (int ni = 0; ni < 4; ++ni) {
    const int col = bn + wn + ni*16 + lq;
    const float bv = bias ? bias[col] : 0.f;
#pragma unroll
    for (int mi = 0; mi < 4; ++mi) {
#pragma unroll
      for (int r = 0; r < 4; ++r) {
        const int row = bm + wm + mi*16 + q*4 + r;
        float v = acc[mi][ni][r] + bv;
        if (relu) v = fmaxf(v, 0.f);
        if (Cf) Cf[row*N + col] = v;
        if (Cb) Cb[row*N + col] = f2bf(v);
      }
    }
  }
}

// ---------------- flash-style attention (bf16 in/out), DH=16 ----------------
__global__ __launch_bounds__(64) void attn_kernel(const short* __restrict__ QKV,
                                                  short* __restrict__ O) {
  int blk = blockIdx.x;
  int qt = blk & 7;
  int h  = (blk >> 3) & 7;
  int b  = blk >> 6;
  int tid = threadIdx.x;
  int qrow = b*512 + qt*64 + tid;
  int col0 = h*16;
  float q[16], o[16];
  {
    short8 q0 = *(const short8*)&QKV[qrow*384 + col0];
    short8 q1 = *(const short8*)&QKV[qrow*384 + col0 + 8];
#pragma unroll
    for (int d = 0; d < 8; ++d) { q[d] = bfdec((unsigned short)q0[d]); o[d] = 0.f; }
#pragma unroll
    for (int d = 0; d < 8; ++d) { q[8+d] = bfdec((unsigned short)q1[d]); o[8+d] = 0.f; }
  }
  float mM = -1e30f, lsum = 0.f;
  __shared__ float kv[64][16];
  __shared__ float vv[64][16];
  for (int kt = 0; kt < 8; ++kt) {
    __syncthreads();
    int krow = b*512 + kt*64 + tid;
    {
      short8 k0 = *(const short8*)&QKV[krow*384 + 128 + col0];
      short8 k1 = *(const short8*)&QKV[krow*384 + 128 + col0 + 8];
      short8 v0 = *(const short8*)&QKV[krow*384 + 256 + col0];
      short8 v1 = *(const short8*)&QKV[krow*384 + 256 + col0 + 8];
#pragma unroll
      for (int d = 0; d < 8; ++d) {
        kv[tid][d]   = bfdec((unsigned short)k0[d]);
        kv[tid][8+d] = bfdec((unsigned short)k1[d]);
        vv[tid][d]   = bfdec((unsigned short)v0[d]);
        vv[tid][8+d] = bfdec((unsigned short)v1[d]);
      }
    }
    __syncthreads();
    float s[64];
    float tmax = -1e30f;
#pragma unroll
    for (int c = 0; c < 64; ++c) {
      float a = 0.f;
#pragma unroll
      for (int d = 0; d < 16; ++d) a += q[d]*kv[c][d];
      a *= 0.25f;       // 1/sqrt(DH)
      s[c] = a;
      tmax = fmaxf(tmax, a);
    }
    float mNew = fmaxf(mM, tmax);
    float alpha = __expf(mM - mNew);
    lsum *= alpha;
#pragma unroll
    for (int d = 0; d < 16; ++d) o[d] *= alpha;
#pragma unroll
    for (int c = 0; c < 64; ++c) {
      float p = __expf(s[c] - mNew);
      lsum += p;
#pragma unroll
      for (int d = 0; d < 16; ++d) o[d] += p*vv[c][d];
    }
    mM = mNew;
  }
  float inv = 1.f / lsum;
#pragma unroll
  for (int d = 0; d < 16; ++d) O[qrow*128 + col0 + d] = f2bf(o[d]*inv);
}

// ---------------- residual + LayerNorm (D=128): x fp32 + bf16 mirror ----------------
__global__ __launch_bounds__(128) void resln_kernel(float* __restrict__ x,
    const float* __restrict__ r, const float* __restrict__ g,
    const float* __restrict__ bta, short* __restrict__ xbf) {
  int row = blockIdx.x, j = threadIdx.x;
  int idx = row*128 + j;
  float v = x[idx] + r[idx];
  __shared__ float sm[2], sv[2];
  float s = wsum64(v);
  if ((j & 63) == 0) sm[j >> 6] = s;
  __syncthreads();
  float mean = (sm[0] + sm[1]) * (1.f / 128.f);
  float d = v - mean;
  float qq = wsum64(d * d);
  if ((j & 63) == 0) sv[j >> 6] = qq;
  __syncthreads();
  float var = (sv[0] + sv[1]) * (1.f / 128.f);
  float o = d * rsqrtf(var + 1e-5f) * g[j] + bta[j];
  x[idx] = o;
  xbf[idx] = f2bf(o);
}

// ---------------- mean-pool + 2-layer classifier ----------------
__global__ __launch_bounds__(128) void pool_cls_kernel(const float* __restrict__ W,
                                                       float* __restrict__ outf) {
  int b = blockIdx.x, j = threadIdx.x;
  float s = 0.f;
  for (int ss = 0; ss < 512; ++ss) s += W[OFF_X + ((b*512 + ss)*128) + j];
  __shared__ float pooled[128];
  __shared__ float hid[64];
  pooled[j] = s * (1.f / 512.f);
  __syncthreads();
  if (j < 64) {
    float a = W[OFF_CB1 + j];
    for (int i = 0; i < 128; ++i) a += pooled[i] * W[OFF_CW1 + i*64 + j];
    hid[j] = fmaxf(a, 0.f);
  }
  __syncthreads();
  if (j < 5) {
    float a = W[OFF_CB2 + j];
    for (int i = 0; i < 64; ++i) a += hid[i] * W[OFF_CW2 + i*5 + j];
    outf[b*5 + j] = a;
  }
}

// ---------------- launch ----------------
extern "C" void kernel_launch(void* const* d_in, const int* in_sizes, int n_in,
                              void* d_out, int out_size, void* d_ws, size_t ws_size,
                              hipStream_t stream) {
  (void)in_sizes; (void)out_size; (void)ws_size;
  float* W = reinterpret_cast<float*>(d_ws);
  float* outf = reinterpret_cast<float*>(d_out);
  short* sdebf = (short*)(W + OFF_SDEBF);
  short* xbf   = (short*)(W + OFF_XBF);
  short* qkvbf = (short*)(W + OFF_QKVBF);
  short* obf   = (short*)(W + OFF_OBF);
  short* hbf   = (short*)(W + OFF_HBF);
  PtrPack pk;
  for (int i = 0; i < 45 && i < n_in; ++i) pk.p[i] = d_in[i];

  ingest_kernel<<<512, 256, 0, stream>>>(pk, W);
  prep_kernel<<<512, 256, 0, stream>>>(W);
  encoder_kernel<<<16384, 64, 0, stream>>>(W, outf);
  precompute_kernel<<<5110, 128, 0, stream>>>(W);
  sde_kernel<<<22, 256, 0, stream>>>(W, d_in[2], outf);

  // x = sde_features @ in_w + in_b  (fp32 master + bf16 mirror)
  gemm_bf16_kernel<<<dim3(128, 1), 256, 0, stream>>>(sdebf, (short*)(W + OFF_INWT),
      W + OFF_INB, W + OFF_X, xbf, 128, 64, 0);
  for (int l = 0; l < 4; ++l) {
    gemm_bf16_kernel<<<dim3(128, 3), 256, 0, stream>>>(xbf,
        (short*)(W + OFF_WQKVT) + l*49152, W + OFF_BQKV + l*384,
        (float*)nullptr, qkvbf, 384, 128, 0);
    attn_kernel<<<2048, 64, 0, stream>>>(qkvbf, obf);
    gemm_bf16_kernel<<<dim3(128, 1), 256, 0, stream>>>(obf,
        (short*)(W + OFF_WOT) + l*16384, W + OFF_BO + l*128,
        W + OFF_TMP, (short*)nullptr, 128, 128, 0);
    resln_kernel<<<16384, 128, 0, stream>>>(W + OFF_X, W + OFF_TMP,
        W + OFF_LN1G + l*128, W + OFF_LN1B + l*128, xbf);
    gemm_bf16_kernel<<<dim3(128, 4), 256, 0, stream>>>(xbf,
        (short*)(W + OFF_FW1T) + l*65536, W + OFF_FB1 + l*512,
        (float*)nullptr, hbf, 512, 128, 1);
    gemm_bf16_kernel<<<dim3(128, 1), 256, 0, stream>>>(hbf,
        (short*)(W + OFF_FW2T) + l*65536, W + OFF_FB2 + l*128,
        W + OFF_TMP, (short*)nullptr, 128, 512, 0);
    resln_kernel<<<16384, 128, 0, stream>>>(W + OFF_X, W + OFF_TMP,
        W + OFF_LN2G + l*128, W + OFF_LN2B + l*128, xbf);
  }
  pool_cls_kernel<<<32, 128, 0, stream>>>(W, outf);
}